// Round 4
// baseline (6372.683 us; speedup 1.0000x reference)
//
#include <hip/hip_runtime.h>
#include <hip/hip_bf16.h>

// LSTM_Sequence_Prediction — MI355X, round 4: persistent-kernel recurrences.
// (round-3 fix: __hip_atomic_fence doesn't exist in this ROCm — use
//  __threadfence(), HIP's agent-scope fence.)
// Encoder layer 0 (256 sequential steps) runs as ONE kernel: weights live in
// VGPRs for the whole sequence, cell state in registers, h exchanged through
// a double-buffered global array with a hand-rolled device-scope grid barrier.
// Decoder (32 steps) likewise. Layers 1..2 and head are one-shot kernels.

constexpr int NB = 64;    // batch
constexpr int NH = 768;   // hidden
constexpr int NF = 256;   // features
constexpr int NS = 256;   // seq len
constexpr int NT = 32;    // target len
constexpr int ENC_BLOCKS = 96;   // 48 unit-tiles x 2 batch halves
constexpr int DEC_BLOCKS = 48;   // 768 units / 16

typedef short bf16x8 __attribute__((ext_vector_type(8)));
typedef float f32x4 __attribute__((ext_vector_type(4)));

__device__ __forceinline__ float sigm(float x) { return 1.f / (1.f + expf(-x)); }

// Device-scope grid barrier (all blocks co-resident by construction: grid <=
// 96 blocks of 256 thr, well under any occupancy bound on 256 CUs).
// __threadfence() (agent scope) publishes h-writes before the rendezvous and
// invalidates stale cached reads after it.
__device__ __forceinline__ void grid_barrier(int* cnt, int* flag, int phase, int nb) {
    __syncthreads();
    if (threadIdx.x == 0) {
        __threadfence();
        const int prev = __hip_atomic_fetch_add(cnt, 1, __ATOMIC_ACQ_REL, __HIP_MEMORY_SCOPE_AGENT);
        if (prev == nb - 1) {
            __hip_atomic_store(cnt, 0, __ATOMIC_RELAXED, __HIP_MEMORY_SCOPE_AGENT);
            __hip_atomic_store(flag, phase, __ATOMIC_RELEASE, __HIP_MEMORY_SCOPE_AGENT);
        } else {
            while (__hip_atomic_load(flag, __ATOMIC_ACQUIRE, __HIP_MEMORY_SCOPE_AGENT) < phase)
                __builtin_amdgcn_s_sleep(1);
        }
        __threadfence();
    }
    __syncthreads();
}

// fp32 -> bf16 conversion, 4 elements/thread (n % 4 == 0 for all our arrays)
__global__ __launch_bounds__(256) void cvt_f32_bf16(
    const float* __restrict__ s, __hip_bfloat16* __restrict__ d, int n)
{
    const int i = (blockIdx.x * 256 + threadIdx.x) * 4;
    if (i >= n) return;
    const float4 v = *(const float4*)(s + i);
    d[i]     = __float2bfloat16(v.x);
    d[i + 1] = __float2bfloat16(v.y);
    d[i + 2] = __float2bfloat16(v.z);
    d[i + 3] = __float2bfloat16(v.w);
}

// Persistent encoder layer 0. Block = 4 waves; wave g = gate g for a 16-unit
// tile over 32 batch rows. B-fragments (Wx: 8 chunks, Wh: 24 chunks) are
// loaded into VGPRs ONCE and reused for all 256 steps. c in registers.
__global__ __launch_bounds__(256, 1) void enc_persist(
    const __hip_bfloat16* __restrict__ xb,    // NS x NB x NF bf16
    const __hip_bfloat16* __restrict__ Wx,    // 4H x NF bf16
    const __hip_bfloat16* __restrict__ Wh,    // 4H x NH bf16
    const float* __restrict__ bih, const float* __restrict__ bhh,
    __hip_bfloat16* __restrict__ h0buf,       // NB x NH bf16 (zero-inited)
    __hip_bfloat16* __restrict__ h1buf,       // NB x NH bf16
    float* __restrict__ enc0,                 // NB x NH fp32 (final h out)
    int* cnt, int* flag)
{
    const int bu = blockIdx.x % (NH / 16);    // unit tile (48)
    const int bm = blockIdx.x / (NH / 16);    // batch half (2)
    const int u0 = bu * 16;
    const int tid = threadIdx.x;
    const int g = tid >> 6;                   // wave index == gate index
    const int lane = tid & 63;
    const int r = lane & 15;
    const int q = lane >> 4;
    const int row0 = bm * 32 + r;
    const int row1 = row0 + 16;

    // --- load weight B-fragments into registers (held across all steps) ---
    const size_t wrow = (size_t)(g * NH + u0 + r);
    bf16x8 wx[8], wh[24];
    #pragma unroll
    for (int c = 0; c < 8; ++c)
        wx[c] = *(const bf16x8*)(Wx + wrow * NF + c * 32 + q * 8);
    #pragma unroll
    for (int c = 0; c < 24; ++c)
        wh[c] = *(const bf16x8*)(Wh + wrow * NH + c * 32 + q * 8);

    __shared__ float gbuf[4][32][17];
    __shared__ float lbias[64];               // [gate*16 + u] combined bias
    if (tid < 64)
        lbias[tid] = bih[(tid >> 4) * NH + u0 + (tid & 15)]
                   + bhh[(tid >> 4) * NH + u0 + (tid & 15)];
    __syncthreads();

    float cst[2] = {0.f, 0.f};                // cell state, 2 cells/thread

    for (int t = 0; t < NS; ++t) {
        const __hip_bfloat16* hcur = (t & 1) ? h1buf : h0buf;
        __hip_bfloat16* hnext      = (t & 1) ? h0buf : h1buf;
        const __hip_bfloat16* xt = xb + (size_t)t * NB * NF;

        f32x4 acc0 = {0.f, 0.f, 0.f, 0.f};
        f32x4 acc1 = {0.f, 0.f, 0.f, 0.f};
        #pragma unroll
        for (int c = 0; c < 8; ++c) {
            const bf16x8 a0 = *(const bf16x8*)(xt + (size_t)row0 * NF + c * 32 + q * 8);
            const bf16x8 a1 = *(const bf16x8*)(xt + (size_t)row1 * NF + c * 32 + q * 8);
            acc0 = __builtin_amdgcn_mfma_f32_16x16x32_bf16(a0, wx[c], acc0, 0, 0, 0);
            acc1 = __builtin_amdgcn_mfma_f32_16x16x32_bf16(a1, wx[c], acc1, 0, 0, 0);
        }
        #pragma unroll
        for (int c = 0; c < 24; ++c) {
            const bf16x8 a0 = *(const bf16x8*)(hcur + (size_t)row0 * NH + c * 32 + q * 8);
            const bf16x8 a1 = *(const bf16x8*)(hcur + (size_t)row1 * NH + c * 32 + q * 8);
            acc0 = __builtin_amdgcn_mfma_f32_16x16x32_bf16(a0, wh[c], acc0, 0, 0, 0);
            acc1 = __builtin_amdgcn_mfma_f32_16x16x32_bf16(a1, wh[c], acc1, 0, 0, 0);
        }

        // C/D layout: col = lane&15 (unit), row = (lane>>4)*4 + reg
        #pragma unroll
        for (int i = 0; i < 4; ++i) {
            gbuf[g][q * 4 + i][r]      = acc0[i];
            gbuf[g][16 + q * 4 + i][r] = acc1[i];
        }
        __syncthreads();

        #pragma unroll
        for (int i = 0; i < 2; ++i) {
            const int bl = (tid >> 4) + i * 16;
            const int u  = tid & 15;
            const int gu = u0 + u;
            const int b  = bm * 32 + bl;
            const float pi = gbuf[0][bl][u] + lbias[u];
            const float pf = gbuf[1][bl][u] + lbias[16 + u];
            const float pg = gbuf[2][bl][u] + lbias[32 + u];
            const float po = gbuf[3][bl][u] + lbias[48 + u];
            const float cn = sigm(pf) * cst[i] + sigm(pi) * tanhf(pg);
            const float hn = sigm(po) * tanhf(cn);
            cst[i] = cn;
            hnext[(size_t)b * NH + gu] = __float2bfloat16(hn);
            if (t == NS - 1) enc0[(size_t)b * NH + gu] = hn;
        }
        if (t != NS - 1) grid_barrier(cnt, flag, t + 1, ENC_BLOCKS);
    }
}

// One-shot LSTM step (encoder layers 1..2): gates = xin@Wx^T + b; c_prev = 0.
template<int KX, int KH>
__global__ __launch_bounds__(256) void lstm_step(
    const __hip_bfloat16* __restrict__ xin,   // NB x KX  (bf16)
    const __hip_bfloat16* __restrict__ hin,   // NB x KH  (bf16, null if KH==0)
    const __hip_bfloat16* __restrict__ Wx,    // 4H x KX  (bf16)
    const __hip_bfloat16* __restrict__ Wh,    // 4H x KH  (bf16)
    const float* __restrict__ bih,            // 4H (fp32)
    const float* __restrict__ bhh,            // 4H (fp32)
    const float* __restrict__ c_in,           // NB x NH fp32 or null (=> 0)
    __hip_bfloat16* __restrict__ h_bf,        // NB x NH bf16 (always written)
    float* __restrict__ h_f32,                // NB x NH fp32 or null
    float* __restrict__ c_out)                // NB x NH fp32 or null
{
    constexpr int K = KX + KH;
    constexpr int NCH = K / 32;
    const int bu = blockIdx.x % (NH / 16);
    const int bm = blockIdx.x / (NH / 16);
    const int u0 = bu * 16;
    const int tid = threadIdx.x;
    const int g = tid >> 6;
    const int lane = tid & 63;
    const int r = lane & 15;
    const int q = lane >> 4;

    f32x4 acc0 = {0.f, 0.f, 0.f, 0.f};
    f32x4 acc1 = {0.f, 0.f, 0.f, 0.f};
    const int row0 = bm * 32 + r;
    const int row1 = row0 + 16;
    const long wr = (long)(g * NH + u0 + r);

    #pragma unroll
    for (int c = 0; c < NCH; ++c) {
        const int k0 = c * 32;
        bf16x8 a0, a1, bfrag;
        if (k0 < KX) {
            const int kk = k0 + q * 8;
            a0 = *(const bf16x8*)(xin + (long)row0 * KX + kk);
            a1 = *(const bf16x8*)(xin + (long)row1 * KX + kk);
            bfrag = *(const bf16x8*)(Wx + wr * KX + kk);
        } else {
            const int kk = (k0 - KX) + q * 8;
            a0 = *(const bf16x8*)(hin + (long)row0 * KH + kk);
            a1 = *(const bf16x8*)(hin + (long)row1 * KH + kk);
            bfrag = *(const bf16x8*)(Wh + wr * KH + kk);
        }
        acc0 = __builtin_amdgcn_mfma_f32_16x16x32_bf16(a0, bfrag, acc0, 0, 0, 0);
        acc1 = __builtin_amdgcn_mfma_f32_16x16x32_bf16(a1, bfrag, acc1, 0, 0, 0);
    }

    __shared__ float gbuf[4][32][17];
    #pragma unroll
    for (int i = 0; i < 4; ++i) {
        gbuf[g][q * 4 + i][r]      = acc0[i];
        gbuf[g][16 + q * 4 + i][r] = acc1[i];
    }
    __syncthreads();

    #pragma unroll
    for (int i = 0; i < 2; ++i) {
        const int idx = tid + i * 256;
        const int bl = idx >> 4;
        const int u  = idx & 15;
        const int gu = u0 + u;
        const int b  = bm * 32 + bl;
        const float pi = gbuf[0][bl][u] + bih[gu]          + bhh[gu];
        const float pf = gbuf[1][bl][u] + bih[NH + gu]     + bhh[NH + gu];
        const float pg = gbuf[2][bl][u] + bih[2 * NH + gu] + bhh[2 * NH + gu];
        const float po = gbuf[3][bl][u] + bih[3 * NH + gu] + bhh[3 * NH + gu];
        const float cp = c_in ? c_in[(long)b * NH + gu] : 0.f;
        const float cn = sigm(pf) * cp + sigm(pi) * tanhf(pg);
        const float hn = sigm(po) * tanhf(cn);
        if (c_out) c_out[(long)b * NH + gu] = cn;
        if (h_f32) h_f32[(long)b * NH + gu] = hn;
        h_bf[(long)b * NH + gu] = __float2bfloat16(hn);
    }
}

// Persistent decoder: 32 steps of a single 768-vector recurrence (only layer
// L-1 matters; f-gate dead since c_prev==0). 16 threads per unit, fp32.
__global__ __launch_bounds__(256) void dec_persist(
    const float* __restrict__ W,              // 4H x NH fp32 (d_Wih layer 2)
    const float* __restrict__ bih, const float* __restrict__ bhh,
    float* __restrict__ hd0,                  // NH fp32 (zero-inited)
    float* __restrict__ hd1,                  // NH fp32
    float* __restrict__ hall,                 // NT x NH fp32
    int* cnt, int* flag)
{
    const int ul = threadIdx.x >> 4;
    const int j  = threadIdx.x & 15;
    const int u  = blockIdx.x * 16 + ul;
    const float* Wi = W + (size_t)u * NH;
    const float* Wg = W + (size_t)(2 * NH + u) * NH;
    const float* Wo = W + (size_t)(3 * NH + u) * NH;
    const float bi = bih[u]          + bhh[u];
    const float bg = bih[2 * NH + u] + bhh[2 * NH + u];
    const float bo = bih[3 * NH + u] + bhh[3 * NH + u];

    for (int t = 0; t < NT; ++t) {
        const float* hin = (t & 1) ? hd1 : hd0;
        float* hout      = (t & 1) ? hd0 : hd1;
        float ai = 0.f, ag = 0.f, ao = 0.f;
        for (int k = j; k < NH; k += 16) {
            const float hv = hin[k];
            ai += hv * Wi[k];
            ag += hv * Wg[k];
            ao += hv * Wo[k];
        }
        #pragma unroll
        for (int off = 8; off > 0; off >>= 1) {
            ai += __shfl_xor(ai, off, 16);
            ag += __shfl_xor(ag, off, 16);
            ao += __shfl_xor(ao, off, 16);
        }
        if (j == 0) {
            const float cn = sigm(ai + bi) * tanhf(ag + bg);
            const float hn = sigm(ao + bo) * tanhf(cn);
            hout[u] = hn;
            hall[(size_t)t * NH + u] = hn;
        }
        if (t != NT - 1) grid_barrier(cnt, flag, t + 1, DEC_BLOCKS);
    }
}

// Head: out[t,b,f] = hdec_all[t]@lin_W^T + lin_b, broadcast over batch.
__global__ __launch_bounds__(256) void head_kernel(
    const float* __restrict__ hall,           // NT x NH
    const float* __restrict__ lw,             // NF x NH
    const float* __restrict__ lb,             // NF
    float* __restrict__ out)                  // NT x NB x NF
{
    const int t = blockIdx.x;
    const int f = threadIdx.x;
    const float* h = hall + (size_t)t * NH;
    const float4* wrow = (const float4*)(lw + (size_t)f * NH);
    float acc = 0.f;
    for (int k4 = 0; k4 < NH / 4; ++k4) {
        const float4 w = wrow[k4];
        acc += h[k4 * 4]     * w.x;
        acc += h[k4 * 4 + 1] * w.y;
        acc += h[k4 * 4 + 2] * w.z;
        acc += h[k4 * 4 + 3] * w.w;
    }
    acc += lb[f];
    float* o = out + (size_t)t * NB * NF + f;
    for (int b = 0; b < NB; ++b) o[(size_t)b * NF] = acc;
}

extern "C" void kernel_launch(void* const* d_in, const int* in_sizes, int n_in,
                              void* d_out, int out_size, void* d_ws, size_t ws_size,
                              hipStream_t stream) {
    (void)in_sizes; (void)n_in; (void)out_size; (void)ws_size;
    const float* x     = (const float*)d_in[0];
    const float* eWih0 = (const float*)d_in[1];
    const float* eWhh0 = (const float*)d_in[2];
    const float* ebih0 = (const float*)d_in[3];
    const float* ebhh0 = (const float*)d_in[4];
    const float* eWih  = (const float*)d_in[5];
    // d_in[6] = e_Whh : provably unused (zero state, seq_len=1)
    const float* ebih  = (const float*)d_in[7];
    const float* ebhh  = (const float*)d_in[8];
    const float* dWih  = (const float*)d_in[9];
    // d_in[10] = d_Whh : provably unused
    const float* dbih  = (const float*)d_in[11];
    const float* dbhh  = (const float*)d_in[12];
    const float* linW  = (const float*)d_in[13];
    const float* linb  = (const float*)d_in[14];
    float* out = (float*)d_out;

    // ---- workspace layout (bytes) ----
    char* ws = (char*)d_ws;
    __hip_bfloat16* xb   = (__hip_bfloat16*)(ws);              // 8,388,608 B
    __hip_bfloat16* W0x  = (__hip_bfloat16*)(ws +  8388608);   // 1,572,864 B
    __hip_bfloat16* W0h  = (__hip_bfloat16*)(ws +  9961472);   // 4,718,592 B
    __hip_bfloat16* eW12 = (__hip_bfloat16*)(ws + 14680064);   // 9,437,184 B
    __hip_bfloat16* hb0  = (__hip_bfloat16*)(ws + 24117248);   // 98,304 B
    __hip_bfloat16* hb1  = (__hip_bfloat16*)(ws + 24215552);   // 98,304 B
    float* hd0  = (float*)(ws + 24313856);                     // 3,072 B
    float* hd1  = (float*)(ws + 24316928);                     // 3,072 B
    float* hall = (float*)(ws + 24320000);                     // 98,304 B
    int* bar    = (int*)(ws + 24418304);                       // 512 B
    int* enc_cnt  = bar;          // +0
    int* enc_flag = bar + 32;     // +128 B
    int* dec_cnt  = bar + 64;     // +256 B
    int* dec_flag = bar + 96;     // +384 B

    // zero initial states + barrier vars (ws poisoned 0xAA each call)
    (void)hipMemsetAsync(hb0, 0, (size_t)NB * NH * 2, stream);
    (void)hipMemsetAsync(hd0, 0, (size_t)NH * 4, stream);
    (void)hipMemsetAsync(bar, 0, 512, stream);

    // one-time fp32 -> bf16 conversions (parallel, off the critical path)
    cvt_f32_bf16<<<(NS * NB * NF) / 1024, 256, 0, stream>>>(x, xb, NS * NB * NF);
    cvt_f32_bf16<<<(4 * NH * NF) / 1024, 256, 0, stream>>>(eWih0, W0x, 4 * NH * NF);
    cvt_f32_bf16<<<(4 * NH * NH) / 1024, 256, 0, stream>>>(eWhh0, W0h, 4 * NH * NH);
    cvt_f32_bf16<<<(2 * 4 * NH * NH) / 1024, 256, 0, stream>>>(eWih, eW12, 2 * 4 * NH * NH);

    float* enc = out + (size_t)NT * NB * NF;                   // encoder_hidden slab

    // encoder layer 0: one persistent kernel, 256 internal steps.
    // final h lands in hb0/hb1 ping-pong end + enc[0] (fp32).
    enc_persist<<<ENC_BLOCKS, 256, 0, stream>>>(
        xb, W0x, W0h, ebih0, ebhh0, hb0, hb1, enc, enc_cnt, enc_flag);

    // encoder layers 1..2: single step, zero state, Whh dead.
    // NS=256 even => final h written to hb0 ((t=255)&1 -> hnext=h0buf).
    lstm_step<NH, 0><<<96, 256, 0, stream>>>(
        hb0, nullptr, eW12, nullptr, ebih, ebhh,
        nullptr, hb1, enc + NB * NH, nullptr);
    lstm_step<NH, 0><<<96, 256, 0, stream>>>(
        hb1, nullptr, eW12 + (size_t)4 * NH * NH, nullptr,
        ebih + 4 * NH, ebhh + 4 * NH,
        nullptr, hb0, enc + 2 * (size_t)NB * NH, nullptr);

    // decoder: one persistent kernel, 32 internal steps (layer 2 only)
    const float* W2 = dWih + (size_t)2 * 4 * NH * NH;
    dec_persist<<<DEC_BLOCKS, 256, 0, stream>>>(
        W2, dbih + 2 * 4 * NH, dbhh + 2 * 4 * NH, hd0, hd1, hall,
        dec_cnt, dec_flag);

    // head + batch broadcast
    head_kernel<<<NT, NF, 0, stream>>>(hall, linW, linb, out);
}

// Round 5
// 5859.214 us; speedup vs baseline: 1.0876x; 1.0876x over previous
//
#include <hip/hip_runtime.h>
#include <hip/hip_bf16.h>

// LSTM_Sequence_Prediction — MI355X, round 5.
// Round-4 post-mortem: the centralized atomic-counter grid barrier serialized
// 96 same-line RMWs at the LLC (~22 us/step). Replaced with a slot barrier:
// per-block arrival slots (parallel plain stores), block-0 wave-0 aggregates
// lane-parallel, publishes a monotonic go flag. No RMW anywhere.

constexpr int NB = 64;    // batch
constexpr int NH = 768;   // hidden
constexpr int NF = 256;   // features
constexpr int NS = 256;   // seq len
constexpr int NT = 32;    // target len
constexpr int ENC_BLOCKS = 96;   // 48 unit-tiles x 2 batch halves
constexpr int DEC_BLOCKS = 48;   // 768 units / 16

typedef short bf16x8 __attribute__((ext_vector_type(8)));
typedef float f32x4 __attribute__((ext_vector_type(4)));

__device__ __forceinline__ float sigm(float x) { return 1.f / (1.f + expf(-x)); }

// Serialization-free grid barrier. slots: one int per 16-int (64B) stride per
// block; go: single int. phase must be monotonically increasing from 1.
// All blocks co-resident by construction (<=96 blocks of 256 thr on 256 CUs).
__device__ __forceinline__ void grid_barrier(int* slots, int* go, int phase, int nb) {
    __syncthreads();
    const int tid = threadIdx.x;
    if (tid == 0) {
        __threadfence();   // publish this block's h writes (XCD L2 -> LLC)
        __hip_atomic_store(slots + (int)blockIdx.x * 16, phase,
                           __ATOMIC_RELEASE, __HIP_MEMORY_SCOPE_AGENT);
    }
    if (blockIdx.x == 0 && tid < 64) {
        // lane-parallel aggregation: lane watches slots tid, tid+64, ...
        for (int s = tid; s < nb; s += 64) {
            while (__hip_atomic_load(slots + s * 16, __ATOMIC_RELAXED,
                                     __HIP_MEMORY_SCOPE_AGENT) < phase)
                __builtin_amdgcn_s_sleep(1);
        }
        if (tid == 0) {
            __threadfence();
            __hip_atomic_store(go, phase, __ATOMIC_RELEASE, __HIP_MEMORY_SCOPE_AGENT);
        }
    }
    if (tid == 0) {
        while (__hip_atomic_load(go, __ATOMIC_RELAXED, __HIP_MEMORY_SCOPE_AGENT) < phase)
            __builtin_amdgcn_s_sleep(1);
        __threadfence();   // acquire: drop stale cached h before next step
    }
    __syncthreads();
}

// fp32 -> bf16 conversion, 4 elements/thread (n % 4 == 0 for all our arrays)
__global__ __launch_bounds__(256) void cvt_f32_bf16(
    const float* __restrict__ s, __hip_bfloat16* __restrict__ d, int n)
{
    const int i = (blockIdx.x * 256 + threadIdx.x) * 4;
    if (i >= n) return;
    const float4 v = *(const float4*)(s + i);
    d[i]     = __float2bfloat16(v.x);
    d[i + 1] = __float2bfloat16(v.y);
    d[i + 2] = __float2bfloat16(v.z);
    d[i + 3] = __float2bfloat16(v.w);
}

// Persistent encoder layer 0. Block = 4 waves; wave g = gate g for a 16-unit
// tile over 32 batch rows. c stays in registers; weights stream from L2.
__global__ __launch_bounds__(256, 1) void enc_persist(
    const __hip_bfloat16* __restrict__ xb,    // NS x NB x NF bf16
    const __hip_bfloat16* __restrict__ Wx,    // 4H x NF bf16
    const __hip_bfloat16* __restrict__ Wh,    // 4H x NH bf16
    const float* __restrict__ bih, const float* __restrict__ bhh,
    __hip_bfloat16* __restrict__ h0buf,       // NB x NH bf16 (zero-inited)
    __hip_bfloat16* __restrict__ h1buf,       // NB x NH bf16
    float* __restrict__ enc0,                 // NB x NH fp32 (final h out)
    int* slots, int* go)
{
    const int bu = blockIdx.x % (NH / 16);    // unit tile (48)
    const int bm = blockIdx.x / (NH / 16);    // batch half (2)
    const int u0 = bu * 16;
    const int tid = threadIdx.x;
    const int g = tid >> 6;                   // wave index == gate index
    const int lane = tid & 63;
    const int r = lane & 15;
    const int q = lane >> 4;
    const int row0 = bm * 32 + r;
    const int row1 = row0 + 16;

    const size_t wrow = (size_t)(g * NH + u0 + r);
    bf16x8 wx[8], wh[24];
    #pragma unroll
    for (int c = 0; c < 8; ++c)
        wx[c] = *(const bf16x8*)(Wx + wrow * NF + c * 32 + q * 8);
    #pragma unroll
    for (int c = 0; c < 24; ++c)
        wh[c] = *(const bf16x8*)(Wh + wrow * NH + c * 32 + q * 8);

    __shared__ float gbuf[4][32][17];
    __shared__ float lbias[64];               // [gate*16 + u] combined bias
    if (tid < 64)
        lbias[tid] = bih[(tid >> 4) * NH + u0 + (tid & 15)]
                   + bhh[(tid >> 4) * NH + u0 + (tid & 15)];
    __syncthreads();

    float cst[2] = {0.f, 0.f};                // cell state, 2 cells/thread

    for (int t = 0; t < NS; ++t) {
        const __hip_bfloat16* hcur = (t & 1) ? h1buf : h0buf;
        __hip_bfloat16* hnext      = (t & 1) ? h0buf : h1buf;
        const __hip_bfloat16* xt = xb + (size_t)t * NB * NF;

        f32x4 acc0 = {0.f, 0.f, 0.f, 0.f};
        f32x4 acc1 = {0.f, 0.f, 0.f, 0.f};
        #pragma unroll
        for (int c = 0; c < 8; ++c) {
            const bf16x8 a0 = *(const bf16x8*)(xt + (size_t)row0 * NF + c * 32 + q * 8);
            const bf16x8 a1 = *(const bf16x8*)(xt + (size_t)row1 * NF + c * 32 + q * 8);
            acc0 = __builtin_amdgcn_mfma_f32_16x16x32_bf16(a0, wx[c], acc0, 0, 0, 0);
            acc1 = __builtin_amdgcn_mfma_f32_16x16x32_bf16(a1, wx[c], acc1, 0, 0, 0);
        }
        #pragma unroll
        for (int c = 0; c < 24; ++c) {
            const bf16x8 a0 = *(const bf16x8*)(hcur + (size_t)row0 * NH + c * 32 + q * 8);
            const bf16x8 a1 = *(const bf16x8*)(hcur + (size_t)row1 * NH + c * 32 + q * 8);
            acc0 = __builtin_amdgcn_mfma_f32_16x16x32_bf16(a0, wh[c], acc0, 0, 0, 0);
            acc1 = __builtin_amdgcn_mfma_f32_16x16x32_bf16(a1, wh[c], acc1, 0, 0, 0);
        }

        // C/D layout: col = lane&15 (unit), row = (lane>>4)*4 + reg
        #pragma unroll
        for (int i = 0; i < 4; ++i) {
            gbuf[g][q * 4 + i][r]      = acc0[i];
            gbuf[g][16 + q * 4 + i][r] = acc1[i];
        }
        __syncthreads();

        #pragma unroll
        for (int i = 0; i < 2; ++i) {
            const int bl = (tid >> 4) + i * 16;
            const int u  = tid & 15;
            const int gu = u0 + u;
            const int b  = bm * 32 + bl;
            const float pi = gbuf[0][bl][u] + lbias[u];
            const float pf = gbuf[1][bl][u] + lbias[16 + u];
            const float pg = gbuf[2][bl][u] + lbias[32 + u];
            const float po = gbuf[3][bl][u] + lbias[48 + u];
            const float cn = sigm(pf) * cst[i] + sigm(pi) * tanhf(pg);
            const float hn = sigm(po) * tanhf(cn);
            cst[i] = cn;
            hnext[(size_t)b * NH + gu] = __float2bfloat16(hn);
            if (t == NS - 1) enc0[(size_t)b * NH + gu] = hn;
        }
        if (t != NS - 1) grid_barrier(slots, go, t + 1, ENC_BLOCKS);
    }
}

// One-shot LSTM step (encoder layers 1..2): gates = xin@Wx^T + b; c_prev = 0.
template<int KX, int KH>
__global__ __launch_bounds__(256) void lstm_step(
    const __hip_bfloat16* __restrict__ xin,   // NB x KX  (bf16)
    const __hip_bfloat16* __restrict__ hin,   // NB x KH  (bf16, null if KH==0)
    const __hip_bfloat16* __restrict__ Wx,    // 4H x KX  (bf16)
    const __hip_bfloat16* __restrict__ Wh,    // 4H x KH  (bf16)
    const float* __restrict__ bih,            // 4H (fp32)
    const float* __restrict__ bhh,            // 4H (fp32)
    const float* __restrict__ c_in,           // NB x NH fp32 or null (=> 0)
    __hip_bfloat16* __restrict__ h_bf,        // NB x NH bf16 (always written)
    float* __restrict__ h_f32,                // NB x NH fp32 or null
    float* __restrict__ c_out)                // NB x NH fp32 or null
{
    constexpr int K = KX + KH;
    constexpr int NCH = K / 32;
    const int bu = blockIdx.x % (NH / 16);
    const int bm = blockIdx.x / (NH / 16);
    const int u0 = bu * 16;
    const int tid = threadIdx.x;
    const int g = tid >> 6;
    const int lane = tid & 63;
    const int r = lane & 15;
    const int q = lane >> 4;

    f32x4 acc0 = {0.f, 0.f, 0.f, 0.f};
    f32x4 acc1 = {0.f, 0.f, 0.f, 0.f};
    const int row0 = bm * 32 + r;
    const int row1 = row0 + 16;
    const long wr = (long)(g * NH + u0 + r);

    #pragma unroll
    for (int c = 0; c < NCH; ++c) {
        const int k0 = c * 32;
        bf16x8 a0, a1, bfrag;
        if (k0 < KX) {
            const int kk = k0 + q * 8;
            a0 = *(const bf16x8*)(xin + (long)row0 * KX + kk);
            a1 = *(const bf16x8*)(xin + (long)row1 * KX + kk);
            bfrag = *(const bf16x8*)(Wx + wr * KX + kk);
        } else {
            const int kk = (k0 - KX) + q * 8;
            a0 = *(const bf16x8*)(hin + (long)row0 * KH + kk);
            a1 = *(const bf16x8*)(hin + (long)row1 * KH + kk);
            bfrag = *(const bf16x8*)(Wh + wr * KH + kk);
        }
        acc0 = __builtin_amdgcn_mfma_f32_16x16x32_bf16(a0, bfrag, acc0, 0, 0, 0);
        acc1 = __builtin_amdgcn_mfma_f32_16x16x32_bf16(a1, bfrag, acc1, 0, 0, 0);
    }

    __shared__ float gbuf[4][32][17];
    #pragma unroll
    for (int i = 0; i < 4; ++i) {
        gbuf[g][q * 4 + i][r]      = acc0[i];
        gbuf[g][16 + q * 4 + i][r] = acc1[i];
    }
    __syncthreads();

    #pragma unroll
    for (int i = 0; i < 2; ++i) {
        const int idx = tid + i * 256;
        const int bl = idx >> 4;
        const int u  = idx & 15;
        const int gu = u0 + u;
        const int b  = bm * 32 + bl;
        const float pi = gbuf[0][bl][u] + bih[gu]          + bhh[gu];
        const float pf = gbuf[1][bl][u] + bih[NH + gu]     + bhh[NH + gu];
        const float pg = gbuf[2][bl][u] + bih[2 * NH + gu] + bhh[2 * NH + gu];
        const float po = gbuf[3][bl][u] + bih[3 * NH + gu] + bhh[3 * NH + gu];
        const float cp = c_in ? c_in[(long)b * NH + gu] : 0.f;
        const float cn = sigm(pf) * cp + sigm(pi) * tanhf(pg);
        const float hn = sigm(po) * tanhf(cn);
        if (c_out) c_out[(long)b * NH + gu] = cn;
        if (h_f32) h_f32[(long)b * NH + gu] = hn;
        h_bf[(long)b * NH + gu] = __float2bfloat16(hn);
    }
}

// Persistent decoder: 32 steps of a single 768-vector recurrence (only layer
// L-1 matters; f-gate dead since c_prev==0). 16 threads per unit, fp32.
__global__ __launch_bounds__(256) void dec_persist(
    const float* __restrict__ W,              // 4H x NH fp32 (d_Wih layer 2)
    const float* __restrict__ bih, const float* __restrict__ bhh,
    float* __restrict__ hd0,                  // NH fp32 (zero-inited)
    float* __restrict__ hd1,                  // NH fp32
    float* __restrict__ hall,                 // NT x NH fp32
    int* slots, int* go)
{
    const int ul = threadIdx.x >> 4;
    const int j  = threadIdx.x & 15;
    const int u  = blockIdx.x * 16 + ul;
    const float* Wi = W + (size_t)u * NH;
    const float* Wg = W + (size_t)(2 * NH + u) * NH;
    const float* Wo = W + (size_t)(3 * NH + u) * NH;
    const float bi = bih[u]          + bhh[u];
    const float bg = bih[2 * NH + u] + bhh[2 * NH + u];
    const float bo = bih[3 * NH + u] + bhh[3 * NH + u];

    for (int t = 0; t < NT; ++t) {
        const float* hin = (t & 1) ? hd1 : hd0;
        float* hout      = (t & 1) ? hd0 : hd1;
        float ai = 0.f, ag = 0.f, ao = 0.f;
        for (int k = j; k < NH; k += 16) {
            const float hv = hin[k];
            ai += hv * Wi[k];
            ag += hv * Wg[k];
            ao += hv * Wo[k];
        }
        #pragma unroll
        for (int off = 8; off > 0; off >>= 1) {
            ai += __shfl_xor(ai, off, 16);
            ag += __shfl_xor(ag, off, 16);
            ao += __shfl_xor(ao, off, 16);
        }
        if (j == 0) {
            const float cn = sigm(ai + bi) * tanhf(ag + bg);
            const float hn = sigm(ao + bo) * tanhf(cn);
            hout[u] = hn;
            hall[(size_t)t * NH + u] = hn;
        }
        if (t != NT - 1) grid_barrier(slots, go, t + 1, DEC_BLOCKS);
    }
}

// Head: out[t,b,f] = hdec_all[t]@lin_W^T + lin_b, broadcast over batch.
__global__ __launch_bounds__(256) void head_kernel(
    const float* __restrict__ hall,           // NT x NH
    const float* __restrict__ lw,             // NF x NH
    const float* __restrict__ lb,             // NF
    float* __restrict__ out)                  // NT x NB x NF
{
    const int t = blockIdx.x;
    const int f = threadIdx.x;
    const float* h = hall + (size_t)t * NH;
    const float4* wrow = (const float4*)(lw + (size_t)f * NH);
    float acc = 0.f;
    for (int k4 = 0; k4 < NH / 4; ++k4) {
        const float4 w = wrow[k4];
        acc += h[k4 * 4]     * w.x;
        acc += h[k4 * 4 + 1] * w.y;
        acc += h[k4 * 4 + 2] * w.z;
        acc += h[k4 * 4 + 3] * w.w;
    }
    acc += lb[f];
    float* o = out + (size_t)t * NB * NF + f;
    for (int b = 0; b < NB; ++b) o[(size_t)b * NF] = acc;
}

extern "C" void kernel_launch(void* const* d_in, const int* in_sizes, int n_in,
                              void* d_out, int out_size, void* d_ws, size_t ws_size,
                              hipStream_t stream) {
    (void)in_sizes; (void)n_in; (void)out_size; (void)ws_size;
    const float* x     = (const float*)d_in[0];
    const float* eWih0 = (const float*)d_in[1];
    const float* eWhh0 = (const float*)d_in[2];
    const float* ebih0 = (const float*)d_in[3];
    const float* ebhh0 = (const float*)d_in[4];
    const float* eWih  = (const float*)d_in[5];
    // d_in[6] = e_Whh : provably unused (zero state, seq_len=1)
    const float* ebih  = (const float*)d_in[7];
    const float* ebhh  = (const float*)d_in[8];
    const float* dWih  = (const float*)d_in[9];
    // d_in[10] = d_Whh : provably unused
    const float* dbih  = (const float*)d_in[11];
    const float* dbhh  = (const float*)d_in[12];
    const float* linW  = (const float*)d_in[13];
    const float* linb  = (const float*)d_in[14];
    float* out = (float*)d_out;

    // ---- workspace layout (bytes) ----
    char* ws = (char*)d_ws;
    __hip_bfloat16* xb   = (__hip_bfloat16*)(ws);              // 8,388,608 B
    __hip_bfloat16* W0x  = (__hip_bfloat16*)(ws +  8388608);   // 1,572,864 B
    __hip_bfloat16* W0h  = (__hip_bfloat16*)(ws +  9961472);   // 4,718,592 B
    __hip_bfloat16* eW12 = (__hip_bfloat16*)(ws + 14680064);   // 9,437,184 B
    __hip_bfloat16* hb0  = (__hip_bfloat16*)(ws + 24117248);   // 98,304 B
    __hip_bfloat16* hb1  = (__hip_bfloat16*)(ws + 24215552);   // 98,304 B
    float* hd0  = (float*)(ws + 24313856);                     // 3,072 B
    float* hd1  = (float*)(ws + 24316928);                     // 3,072 B
    float* hall = (float*)(ws + 24320000);                     // 98,304 B
    int* bar    = (int*)(ws + 24418304);                       // 16,384 B
    int* enc_slots = bar;                  // 96 x 64B = 6144 B
    int* enc_go    = bar + 1536;           // +6144 B (own line)
    int* dec_slots = bar + 1568;           // +6272 B: 48 x 64B = 3072 B
    int* dec_go    = bar + 2336;           // +9344 B (own line)

    // zero initial states + barrier vars (ws poisoned 0xAA each call)
    (void)hipMemsetAsync(hb0, 0, (size_t)NB * NH * 2, stream);
    (void)hipMemsetAsync(hd0, 0, (size_t)NH * 4, stream);
    (void)hipMemsetAsync(bar, 0, 16384, stream);

    // one-time fp32 -> bf16 conversions (parallel, off the critical path)
    cvt_f32_bf16<<<(NS * NB * NF) / 1024, 256, 0, stream>>>(x, xb, NS * NB * NF);
    cvt_f32_bf16<<<(4 * NH * NF) / 1024, 256, 0, stream>>>(eWih0, W0x, 4 * NH * NF);
    cvt_f32_bf16<<<(4 * NH * NH) / 1024, 256, 0, stream>>>(eWhh0, W0h, 4 * NH * NH);
    cvt_f32_bf16<<<(2 * 4 * NH * NH) / 1024, 256, 0, stream>>>(eWih, eW12, 2 * 4 * NH * NH);

    float* enc = out + (size_t)NT * NB * NF;                   // encoder_hidden slab

    // encoder layer 0: one persistent kernel, 256 internal steps.
    enc_persist<<<ENC_BLOCKS, 256, 0, stream>>>(
        xb, W0x, W0h, ebih0, ebhh0, hb0, hb1, enc, enc_slots, enc_go);

    // encoder layers 1..2: single step, zero state, Whh dead.
    // NS=256 even => final h written to hb0 ((t=255)&1 -> hnext=h0buf).
    lstm_step<NH, 0><<<96, 256, 0, stream>>>(
        hb0, nullptr, eW12, nullptr, ebih, ebhh,
        nullptr, hb1, enc + NB * NH, nullptr);
    lstm_step<NH, 0><<<96, 256, 0, stream>>>(
        hb1, nullptr, eW12 + (size_t)4 * NH * NH, nullptr,
        ebih + 4 * NH, ebhh + 4 * NH,
        nullptr, hb0, enc + 2 * (size_t)NB * NH, nullptr);

    // decoder: one persistent kernel, 32 internal steps (layer 2 only)
    const float* W2 = dWih + (size_t)2 * 4 * NH * NH;
    dec_persist<<<DEC_BLOCKS, 256, 0, stream>>>(
        W2, dbih + 2 * 4 * NH, dbhh + 2 * 4 * NH, hd0, hd1, hall,
        dec_slots, dec_go);

    // head + batch broadcast
    head_kernel<<<NT, NF, 0, stream>>>(hall, linW, linb, out);
}

// Round 6
// 1865.501 us; speedup vs baseline: 3.4161x; 3.1408x over previous
//
#include <hip/hip_runtime.h>
#include <hip/hip_bf16.h>

// LSTM_Sequence_Prediction — MI355X, round 6: fence-free persistent recurrence.
// R4/R5 post-mortem: __threadfence() (buffer_wbl2/inv) per step was the wall
// (~20 us/step, MfmaUtil<1%). This version has ZERO cache-maintenance ops:
// cross-block data (h, barrier slots) uses sc0+sc1 (LLC-direct) accesses;
// release = s_waitcnt vmcnt(0); acquire = nothing (sc1 reads can't be stale).
// Weights/x stay ordinary cached loads and remain L1/L2-warm across steps.

constexpr int NB = 64;    // batch
constexpr int NH = 768;   // hidden
constexpr int NF = 256;   // features
constexpr int NS = 256;   // seq len
constexpr int NT = 32;    // target len
constexpr int ENC_BLOCKS = 96;   // 48 unit-tiles x 2 batch halves
constexpr int DEC_BLOCKS = 48;   // 768 units / 16

typedef short bf16x8 __attribute__((ext_vector_type(8)));
typedef float f32x4 __attribute__((ext_vector_type(4)));

__device__ __forceinline__ float sigm(float x) { return 1.f / (1.f + expf(-x)); }

// LLC-direct (coherent) accesses: sc0 sc1 bypass L1 and the non-coherent XCD L2.
__device__ __forceinline__ int4 ld_i4_cohere(const int4* p) {
    int4 v;
    asm volatile("global_load_dwordx4 %0, %1, off sc0 sc1" : "=v"(v) : "v"(p));
    return v;   // NOT ready until vm_drain()!
}
__device__ __forceinline__ void st_i1_cohere(int* p, int v) {
    asm volatile("global_store_dword %0, %1, off sc0 sc1" :: "v"(p), "v"(v) : "memory");
}
__device__ __forceinline__ void vm_drain() {
    asm volatile("s_waitcnt vmcnt(0)" ::: "memory");
}

// All-to-all barrier: block arrival = relaxed slot store (after vm_drain of the
// data stores); wait = wave-0 lanes each watch one slot. Phases monotonic.
__device__ __forceinline__ void arrive(int* slots, int phase) {
    if (threadIdx.x == 0)
        __hip_atomic_store(slots + (int)blockIdx.x * 16, phase,
                           __ATOMIC_RELAXED, __HIP_MEMORY_SCOPE_AGENT);
}
__device__ __forceinline__ void wait_all(int* slots, int phase, int nb) {
    if (threadIdx.x < 64)
        for (int s = threadIdx.x; s < nb; s += 64)
            while (__hip_atomic_load(slots + s * 16, __ATOMIC_RELAXED,
                                     __HIP_MEMORY_SCOPE_AGENT) < phase)
                __builtin_amdgcn_s_sleep(1);
    __syncthreads();
}

// fp32 -> bf16 conversion, 4 elements/thread
__global__ __launch_bounds__(256) void cvt_f32_bf16(
    const float* __restrict__ s, __hip_bfloat16* __restrict__ d, int n)
{
    const int i = (blockIdx.x * 256 + threadIdx.x) * 4;
    if (i >= n) return;
    const float4 v = *(const float4*)(s + i);
    d[i]     = __float2bfloat16(v.x);
    d[i + 1] = __float2bfloat16(v.y);
    d[i + 2] = __float2bfloat16(v.z);
    d[i + 3] = __float2bfloat16(v.w);
}

// Persistent encoder layer 0. 96 blocks; block = 4 waves; wave g = gate g for
// a 16-unit tile over 32 batch rows. h crosses blocks as packed bf16-pairs in
// int arrays (NB x 384), LLC-direct; staged into LDS each step.
__global__ __launch_bounds__(256, 1) void enc_persist(
    const __hip_bfloat16* __restrict__ xb,    // NS x NB x NF bf16 (cached)
    const __hip_bfloat16* __restrict__ Wx,    // 4H x NF bf16 (cached)
    const __hip_bfloat16* __restrict__ Wh,    // 4H x NH bf16 (cached)
    const float* __restrict__ bih, const float* __restrict__ bhh,
    int* __restrict__ h0buf,                  // NB x 384 int (zero-inited)
    int* __restrict__ h1buf,                  // NB x 384 int
    float* __restrict__ enc0,                 // NB x NH fp32 (final h out)
    int* slots)
{
    const int bu = blockIdx.x % (NH / 16);    // unit tile (48)
    const int bm = blockIdx.x / (NH / 16);    // batch half (2)
    const int u0 = bu * 16;
    const int tid = threadIdx.x;
    const int g = tid >> 6;                   // wave index == gate index
    const int lane = tid & 63;
    const int r = lane & 15;
    const int q = lane >> 4;
    const int row0 = bm * 32 + r;
    const int row1 = row0 + 16;

    // weight B-fragments (ordinary cached loads; stay warm in L1/L2 — no
    // invalidates anywhere in this kernel)
    const size_t wrow = (size_t)(g * NH + u0 + r);
    bf16x8 wx[8], wh[24];
    #pragma unroll
    for (int c = 0; c < 8; ++c)
        wx[c] = *(const bf16x8*)(Wx + wrow * NF + c * 32 + q * 8);
    #pragma unroll
    for (int c = 0; c < 24; ++c)
        wh[c] = *(const bf16x8*)(Wh + wrow * NH + c * 32 + q * 8);

    // LDS: staged h (32 rows x 388 ints, +4-int pad => 2-way-max bank aliasing)
    __shared__ int   hst[32 * 388];           // 49,664 B
    __shared__ float gbuf[4][32][17];         //  8,704 B
    __shared__ float lbias[64];
    if (tid < 64)
        lbias[tid] = bih[(tid >> 4) * NH + u0 + (tid & 15)]
                   + bhh[(tid >> 4) * NH + u0 + (tid & 15)];
    __syncthreads();

    float cst[2] = {0.f, 0.f};                // cell state: (rowl, u0+2p), (rowl, u0+2p+1)

    for (int t = 0; t < NS; ++t) {
        const int* hcur = (t & 1) ? h1buf : h0buf;
        int* hnext      = (t & 1) ? h0buf : h1buf;
        const __hip_bfloat16* xt = xb + (size_t)t * NB * NF;

        // ---- x-part (independent of h_t): runs before the barrier wait ----
        f32x4 acc0 = {0.f, 0.f, 0.f, 0.f};
        f32x4 acc1 = {0.f, 0.f, 0.f, 0.f};
        #pragma unroll
        for (int c = 0; c < 8; ++c) {
            const bf16x8 a0 = *(const bf16x8*)(xt + (size_t)row0 * NF + c * 32 + q * 8);
            const bf16x8 a1 = *(const bf16x8*)(xt + (size_t)row1 * NF + c * 32 + q * 8);
            acc0 = __builtin_amdgcn_mfma_f32_16x16x32_bf16(a0, wx[c], acc0, 0, 0, 0);
            acc1 = __builtin_amdgcn_mfma_f32_16x16x32_bf16(a1, wx[c], acc1, 0, 0, 0);
        }

        if (t > 0) wait_all(slots, t, ENC_BLOCKS);

        // ---- stage this half's h_t (12288 ints) into LDS, LLC-direct ----
        {
            const int4* src = (const int4*)hcur + bm * 3072;
            int4 v[12];
            #pragma unroll
            for (int i = 0; i < 12; ++i) v[i] = ld_i4_cohere(src + i * 256 + tid);
            vm_drain();
            #pragma unroll
            for (int i = 0; i < 12; ++i) {
                const int k = i * 256 + tid;          // int4 index
                const int rw = k / 96, cl = k % 96;   // row, int4-col
                *(int4*)(hst + rw * 388 + cl * 4) = v[i];
            }
        }
        __syncthreads();

        // ---- h-part MFMAs from LDS ----
        #pragma unroll
        for (int c = 0; c < 24; ++c) {
            const bf16x8 a0 = *(const bf16x8*)((const short*)hst + r * 776 + c * 32 + q * 8);
            const bf16x8 a1 = *(const bf16x8*)((const short*)hst + (r + 16) * 776 + c * 32 + q * 8);
            acc0 = __builtin_amdgcn_mfma_f32_16x16x32_bf16(a0, wh[c], acc0, 0, 0, 0);
            acc1 = __builtin_amdgcn_mfma_f32_16x16x32_bf16(a1, wh[c], acc1, 0, 0, 0);
        }

        // C/D layout: col = lane&15 (unit), row = (lane>>4)*4 + reg
        #pragma unroll
        for (int i = 0; i < 4; ++i) {
            gbuf[g][q * 4 + i][r]      = acc0[i];
            gbuf[g][16 + q * 4 + i][r] = acc1[i];
        }
        __syncthreads();

        // ---- fused cell epilogue: 2 adjacent units per thread ----
        {
            const int rowl = tid >> 3, pair = tid & 7;
            const int ua = pair * 2;
            float h2[2];
            #pragma unroll
            for (int e = 0; e < 2; ++e) {
                const int ul = ua + e;
                const float pi = gbuf[0][rowl][ul] + lbias[ul];
                const float pf = gbuf[1][rowl][ul] + lbias[16 + ul];
                const float pg = gbuf[2][rowl][ul] + lbias[32 + ul];
                const float po = gbuf[3][rowl][ul] + lbias[48 + ul];
                const float cn = sigm(pf) * cst[e] + sigm(pi) * tanhf(pg);
                h2[e] = sigm(po) * tanhf(cn);
                cst[e] = cn;
            }
            const int b = bm * 32 + rowl;
            if (t == NS - 1) {
                // final step: plain stores (published by dispatch-end flush)
                enc0[(size_t)b * NH + u0 + ua]     = h2[0];
                enc0[(size_t)b * NH + u0 + ua + 1] = h2[1];
                __hip_bfloat16* hf = (__hip_bfloat16*)hnext;
                hf[(size_t)b * NH + u0 + ua]     = __float2bfloat16(h2[0]);
                hf[(size_t)b * NH + u0 + ua + 1] = __float2bfloat16(h2[1]);
            } else {
                union { __hip_bfloat16 b16; unsigned short s; } c0, c1;
                c0.b16 = __float2bfloat16(h2[0]);
                c1.b16 = __float2bfloat16(h2[1]);
                const int pv = (int)c0.s | ((int)c1.s << 16);
                st_i1_cohere(hnext + (size_t)b * 384 + (u0 >> 1) + pair, pv);
            }
        }
        if (t < NS - 1) {
            vm_drain();          // h stores acked at LLC
            __syncthreads();     // all threads' stores acked
            arrive(slots, t + 1);
        }
    }
}

// One-shot LSTM step (encoder layers 1..2): gates = xin@Wx^T + b; c_prev = 0.
template<int KX, int KH>
__global__ __launch_bounds__(256) void lstm_step(
    const __hip_bfloat16* __restrict__ xin,
    const __hip_bfloat16* __restrict__ hin,
    const __hip_bfloat16* __restrict__ Wx,
    const __hip_bfloat16* __restrict__ Wh,
    const float* __restrict__ bih, const float* __restrict__ bhh,
    const float* __restrict__ c_in,
    __hip_bfloat16* __restrict__ h_bf,
    float* __restrict__ h_f32,
    float* __restrict__ c_out)
{
    constexpr int K = KX + KH;
    constexpr int NCH = K / 32;
    const int bu = blockIdx.x % (NH / 16);
    const int bm = blockIdx.x / (NH / 16);
    const int u0 = bu * 16;
    const int tid = threadIdx.x;
    const int g = tid >> 6;
    const int lane = tid & 63;
    const int r = lane & 15;
    const int q = lane >> 4;

    f32x4 acc0 = {0.f, 0.f, 0.f, 0.f};
    f32x4 acc1 = {0.f, 0.f, 0.f, 0.f};
    const int row0 = bm * 32 + r;
    const int row1 = row0 + 16;
    const long wr = (long)(g * NH + u0 + r);

    #pragma unroll
    for (int c = 0; c < NCH; ++c) {
        const int k0 = c * 32;
        bf16x8 a0, a1, bfrag;
        if (k0 < KX) {
            const int kk = k0 + q * 8;
            a0 = *(const bf16x8*)(xin + (long)row0 * KX + kk);
            a1 = *(const bf16x8*)(xin + (long)row1 * KX + kk);
            bfrag = *(const bf16x8*)(Wx + wr * KX + kk);
        } else {
            const int kk = (k0 - KX) + q * 8;
            a0 = *(const bf16x8*)(hin + (long)row0 * KH + kk);
            a1 = *(const bf16x8*)(hin + (long)row1 * KH + kk);
            bfrag = *(const bf16x8*)(Wh + wr * KH + kk);
        }
        acc0 = __builtin_amdgcn_mfma_f32_16x16x32_bf16(a0, bfrag, acc0, 0, 0, 0);
        acc1 = __builtin_amdgcn_mfma_f32_16x16x32_bf16(a1, bfrag, acc1, 0, 0, 0);
    }

    __shared__ float gbuf[4][32][17];
    #pragma unroll
    for (int i = 0; i < 4; ++i) {
        gbuf[g][q * 4 + i][r]      = acc0[i];
        gbuf[g][16 + q * 4 + i][r] = acc1[i];
    }
    __syncthreads();

    #pragma unroll
    for (int i = 0; i < 2; ++i) {
        const int idx = tid + i * 256;
        const int bl = idx >> 4;
        const int u  = idx & 15;
        const int gu = u0 + u;
        const int b  = bm * 32 + bl;
        const float pi = gbuf[0][bl][u] + bih[gu]          + bhh[gu];
        const float pf = gbuf[1][bl][u] + bih[NH + gu]     + bhh[NH + gu];
        const float pg = gbuf[2][bl][u] + bih[2 * NH + gu] + bhh[2 * NH + gu];
        const float po = gbuf[3][bl][u] + bih[3 * NH + gu] + bhh[3 * NH + gu];
        const float cp = c_in ? c_in[(long)b * NH + gu] : 0.f;
        const float cn = sigm(pf) * cp + sigm(pi) * tanhf(pg);
        const float hn = sigm(po) * tanhf(cn);
        if (c_out) c_out[(long)b * NH + gu] = cn;
        if (h_f32) h_f32[(long)b * NH + gu] = hn;
        h_bf[(long)b * NH + gu] = __float2bfloat16(hn);
    }
}

// Persistent decoder: 32 steps of a single 768-vector recurrence (layer L-1
// only; f-gate dead since c_prev==0). fp32; h via LLC-direct ops; no fences.
__global__ __launch_bounds__(256) void dec_persist(
    const float* __restrict__ W,
    const float* __restrict__ bih, const float* __restrict__ bhh,
    float* __restrict__ hd0, float* __restrict__ hd1,
    float* __restrict__ hall, int* slots)
{
    __shared__ float hstD[768];
    const int tid = threadIdx.x;
    const int ul = tid >> 4;
    const int j  = tid & 15;
    const int u  = blockIdx.x * 16 + ul;
    const float* Wi = W + (size_t)u * NH;
    const float* Wg = W + (size_t)(2 * NH + u) * NH;
    const float* Wo = W + (size_t)(3 * NH + u) * NH;
    const float bi = bih[u]          + bhh[u];
    const float bg = bih[2 * NH + u] + bhh[2 * NH + u];
    const float bo = bih[3 * NH + u] + bhh[3 * NH + u];

    for (int t = 0; t < NT; ++t) {
        const float* hin = (t & 1) ? hd1 : hd0;
        float* hout      = (t & 1) ? hd0 : hd1;
        if (t > 0) wait_all(slots, t, DEC_BLOCKS);
        if (tid < 192) {
            int4 v = ld_i4_cohere((const int4*)hin + tid);
            vm_drain();
            ((int4*)hstD)[tid] = v;
        }
        __syncthreads();
        float ai = 0.f, ag = 0.f, ao = 0.f;
        for (int k = j; k < NH; k += 16) {
            const float hv = hstD[k];
            ai += hv * Wi[k];
            ag += hv * Wg[k];
            ao += hv * Wo[k];
        }
        #pragma unroll
        for (int off = 8; off > 0; off >>= 1) {
            ai += __shfl_xor(ai, off, 16);
            ag += __shfl_xor(ag, off, 16);
            ao += __shfl_xor(ao, off, 16);
        }
        if (j == 0) {
            const float cn = sigm(ai + bi) * tanhf(ag + bg);
            const float hn = sigm(ao + bo) * tanhf(cn);
            hall[(size_t)t * NH + u] = hn;             // plain (read post-dispatch)
            if (t < NT - 1)
                st_i1_cohere((int*)(hout + u), __float_as_int(hn));
        }
        if (t < NT - 1) {
            vm_drain();
            __syncthreads();
            arrive(slots, t + 1);
        }
    }
}

// Head: out[t,b,f] = hdec_all[t]@lin_W^T + lin_b, broadcast over batch.
__global__ __launch_bounds__(256) void head_kernel(
    const float* __restrict__ hall,
    const float* __restrict__ lw,
    const float* __restrict__ lb,
    float* __restrict__ out)
{
    const int t = blockIdx.x;
    const int f = threadIdx.x;
    const float* h = hall + (size_t)t * NH;
    const float4* wrow = (const float4*)(lw + (size_t)f * NH);
    float acc = 0.f;
    for (int k4 = 0; k4 < NH / 4; ++k4) {
        const float4 w = wrow[k4];
        acc += h[k4 * 4]     * w.x;
        acc += h[k4 * 4 + 1] * w.y;
        acc += h[k4 * 4 + 2] * w.z;
        acc += h[k4 * 4 + 3] * w.w;
    }
    acc += lb[f];
    float* o = out + (size_t)t * NB * NF + f;
    for (int b = 0; b < NB; ++b) o[(size_t)b * NF] = acc;
}

extern "C" void kernel_launch(void* const* d_in, const int* in_sizes, int n_in,
                              void* d_out, int out_size, void* d_ws, size_t ws_size,
                              hipStream_t stream) {
    (void)in_sizes; (void)n_in; (void)out_size; (void)ws_size;
    const float* x     = (const float*)d_in[0];
    const float* eWih0 = (const float*)d_in[1];
    const float* eWhh0 = (const float*)d_in[2];
    const float* ebih0 = (const float*)d_in[3];
    const float* ebhh0 = (const float*)d_in[4];
    const float* eWih  = (const float*)d_in[5];
    // d_in[6] = e_Whh : provably unused
    const float* ebih  = (const float*)d_in[7];
    const float* ebhh  = (const float*)d_in[8];
    const float* dWih  = (const float*)d_in[9];
    // d_in[10] = d_Whh : provably unused
    const float* dbih  = (const float*)d_in[11];
    const float* dbhh  = (const float*)d_in[12];
    const float* linW  = (const float*)d_in[13];
    const float* linb  = (const float*)d_in[14];
    float* out = (float*)d_out;

    // ---- workspace layout (bytes) ----
    char* ws = (char*)d_ws;
    __hip_bfloat16* xb   = (__hip_bfloat16*)(ws);              // 8,388,608 B
    __hip_bfloat16* W0x  = (__hip_bfloat16*)(ws +  8388608);   // 1,572,864 B
    __hip_bfloat16* W0h  = (__hip_bfloat16*)(ws +  9961472);   // 4,718,592 B
    __hip_bfloat16* eW12 = (__hip_bfloat16*)(ws + 14680064);   // 9,437,184 B
    int* hbi0 = (int*)(ws + 24117248);                         // 98,304 B (NB x 384)
    int* hbi1 = (int*)(ws + 24215552);                         // 98,304 B
    float* hd0  = (float*)(ws + 24313856);                     // 3,072 B
    float* hd1  = (float*)(ws + 24316928);                     // 3,072 B
    float* hall = (float*)(ws + 24320000);                     // 98,304 B
    int* bar    = (int*)(ws + 24418304);                       // 16,384 B
    int* enc_slots = bar;                  // 96 x 64 B
    int* dec_slots = bar + 1536;           // 48 x 64 B

    // zero initial states + barrier slots (ws poisoned 0xAA each call)
    (void)hipMemsetAsync(hbi0, 0, (size_t)NB * NH * 2, stream);
    (void)hipMemsetAsync(hd0, 0, (size_t)NH * 4, stream);
    (void)hipMemsetAsync(bar, 0, 16384, stream);

    // one-time fp32 -> bf16 conversions
    cvt_f32_bf16<<<(NS * NB * NF) / 1024, 256, 0, stream>>>(x, xb, NS * NB * NF);
    cvt_f32_bf16<<<(4 * NH * NF) / 1024, 256, 0, stream>>>(eWih0, W0x, 4 * NH * NF);
    cvt_f32_bf16<<<(4 * NH * NH) / 1024, 256, 0, stream>>>(eWhh0, W0h, 4 * NH * NH);
    cvt_f32_bf16<<<(2 * 4 * NH * NH) / 1024, 256, 0, stream>>>(eWih, eW12, 2 * 4 * NH * NH);

    float* enc = out + (size_t)NT * NB * NF;                   // encoder_hidden slab

    // encoder layer 0: one persistent kernel, 256 internal steps
    enc_persist<<<ENC_BLOCKS, 256, 0, stream>>>(
        xb, W0x, W0h, ebih0, ebhh0, hbi0, hbi1, enc, enc_slots);

    // encoder layers 1..2 (final enc h lands in hbi0 viewed as bf16: t=255 odd -> h0buf)
    __hip_bfloat16* hb0 = (__hip_bfloat16*)hbi0;
    __hip_bfloat16* hb1 = (__hip_bfloat16*)hbi1;
    lstm_step<NH, 0><<<96, 256, 0, stream>>>(
        hb0, nullptr, eW12, nullptr, ebih, ebhh,
        nullptr, hb1, enc + NB * NH, nullptr);
    lstm_step<NH, 0><<<96, 256, 0, stream>>>(
        hb1, nullptr, eW12 + (size_t)4 * NH * NH, nullptr,
        ebih + 4 * NH, ebhh + 4 * NH,
        nullptr, hb0, enc + 2 * (size_t)NB * NH, nullptr);

    // decoder: one persistent kernel, 32 internal steps (layer 2 only)
    const float* W2 = dWih + (size_t)2 * 4 * NH * NH;
    dec_persist<<<DEC_BLOCKS, 256, 0, stream>>>(
        W2, dbih + 2 * 4 * NH, dbhh + 2 * 4 * NH, hd0, hd1, hall, dec_slots);

    // head + batch broadcast
    head_kernel<<<NT, NF, 0, stream>>>(hall, linW, linb, out);
}

// Round 7
// 1792.263 us; speedup vs baseline: 3.5557x; 1.0409x over previous
//
#include <hip/hip_runtime.h>
#include <hip/hip_bf16.h>

// LSTM_Sequence_Prediction — MI355X, round 7.
// R6 (fence-free LLC exchange) = 1866 us, enc 5.76 us/step, CU ~94% idle =>
// latency-chain bound. This round: (1) encoder barrier split into two
// independent 48-block groups (batch halves are provably independent) so each
// polling lane watches exactly ONE slot (R6 had lanes serially polling two);
// (2) polls via explicit sc0+sc1 asm loads; (3) the 4 fp32->bf16 conversion
// kernels fused into one.

constexpr int NB = 64;    // batch
constexpr int NH = 768;   // hidden
constexpr int NF = 256;   // features
constexpr int NS = 256;   // seq len
constexpr int NT = 32;    // target len
constexpr int ENC_BLOCKS = 96;   // 48 unit-tiles x 2 batch halves
constexpr int ENC_GROUP  = 48;   // blocks per batch-half barrier group
constexpr int DEC_BLOCKS = 48;   // 768 units / 16

typedef short bf16x8 __attribute__((ext_vector_type(8)));
typedef float f32x4 __attribute__((ext_vector_type(4)));

__device__ __forceinline__ float sigm(float x) { return 1.f / (1.f + expf(-x)); }

// LLC-direct (coherent) accesses: sc0 sc1 bypass L1 and the non-coherent XCD L2.
__device__ __forceinline__ int4 ld_i4_cohere(const int4* p) {
    int4 v;
    asm volatile("global_load_dwordx4 %0, %1, off sc0 sc1" : "=v"(v) : "v"(p));
    return v;   // NOT ready until vm_drain()!
}
__device__ __forceinline__ int ld_i1_cohere_sync(const int* p) {
    int v;
    asm volatile("global_load_dword %0, %1, off sc0 sc1\n\ts_waitcnt vmcnt(0)"
                 : "=v"(v) : "v"(p) : "memory");
    return v;
}
__device__ __forceinline__ void st_i1_cohere(int* p, int v) {
    asm volatile("global_store_dword %0, %1, off sc0 sc1" :: "v"(p), "v"(v) : "memory");
}
__device__ __forceinline__ void vm_drain() {
    asm volatile("s_waitcnt vmcnt(0)" ::: "memory");
}

// Group barrier: arrival = coherent slot store (after data drained); wait =
// wave-0 lane i watches slot i (nb <= 64: exactly one slot per lane).
__device__ __forceinline__ void arrive(int* slots, int idx, int phase) {
    if (threadIdx.x == 0) st_i1_cohere(slots + idx * 16, phase);
}
__device__ __forceinline__ void wait_all(int* slots, int phase, int nb) {
    if (threadIdx.x < nb) {
        const int* p = slots + threadIdx.x * 16;
        while (ld_i1_cohere_sync(p) < phase) __builtin_amdgcn_s_sleep(1);
    }
    __syncthreads();
}

// Fused fp32 -> bf16 conversion for all four regions (dst contiguous in ws).
__global__ __launch_bounds__(256) void cvt_all(
    const float* __restrict__ s0,   //       4,194,304 el (x)
    const float* __restrict__ s1,   //         786,432 el (e_Wih0)
    const float* __restrict__ s2,   //       2,359,296 el (e_Whh0)
    const float* __restrict__ s3,   //       4,718,592 el (e_Wih[0..1])
    __hip_bfloat16* __restrict__ d) // 12,058,624 el total
{
    const int i = (blockIdx.x * 256 + threadIdx.x) * 4;
    const float* s; int off;
    if (i < 4194304)      { s = s0; off = 0; }
    else if (i < 4980736) { s = s1; off = 4194304; }
    else if (i < 7340032) { s = s2; off = 4980736; }
    else                  { s = s3; off = 7340032; }
    const float4 v = *(const float4*)(s + (i - off));
    d[i]     = __float2bfloat16(v.x);
    d[i + 1] = __float2bfloat16(v.y);
    d[i + 2] = __float2bfloat16(v.z);
    d[i + 3] = __float2bfloat16(v.w);
}

// Persistent encoder layer 0. 96 blocks; block = 4 waves; wave g = gate g for
// a 16-unit tile over 32 batch rows. h crosses blocks as packed bf16-pairs,
// LLC-direct; barrier is per-batch-half (48 blocks).
__global__ __launch_bounds__(256, 1) void enc_persist(
    const __hip_bfloat16* __restrict__ xb,    // NS x NB x NF bf16 (cached)
    const __hip_bfloat16* __restrict__ Wx,    // 4H x NF bf16 (cached)
    const __hip_bfloat16* __restrict__ Wh,    // 4H x NH bf16 (cached)
    const float* __restrict__ bih, const float* __restrict__ bhh,
    int* __restrict__ h0buf,                  // NB x 384 int (zero-inited)
    int* __restrict__ h1buf,                  // NB x 384 int
    float* __restrict__ enc0,                 // NB x NH fp32 (final h out)
    int* slots)                               // 2 groups x 48 x 16 ints
{
    const int bu = blockIdx.x % (NH / 16);    // unit tile (48)
    const int bm = blockIdx.x / (NH / 16);    // batch half (2)
    int* gslots = slots + bm * ENC_GROUP * 16;
    const int u0 = bu * 16;
    const int tid = threadIdx.x;
    const int g = tid >> 6;                   // wave index == gate index
    const int lane = tid & 63;
    const int r = lane & 15;
    const int q = lane >> 4;
    const int row0 = bm * 32 + r;
    const int row1 = row0 + 16;

    // weight B-fragments (ordinary cached loads; L1/L2 stay warm — no
    // invalidates anywhere in this kernel)
    const size_t wrow = (size_t)(g * NH + u0 + r);
    bf16x8 wx[8], wh[24];
    #pragma unroll
    for (int c = 0; c < 8; ++c)
        wx[c] = *(const bf16x8*)(Wx + wrow * NF + c * 32 + q * 8);
    #pragma unroll
    for (int c = 0; c < 24; ++c)
        wh[c] = *(const bf16x8*)(Wh + wrow * NH + c * 32 + q * 8);

    // LDS: staged h (32 rows x 388 ints, +4-int pad)
    __shared__ int   hst[32 * 388];           // 49,664 B
    __shared__ float gbuf[4][32][17];         //  8,704 B
    __shared__ float lbias[64];
    if (tid < 64)
        lbias[tid] = bih[(tid >> 4) * NH + u0 + (tid & 15)]
                   + bhh[(tid >> 4) * NH + u0 + (tid & 15)];
    __syncthreads();

    float cst[2] = {0.f, 0.f};                // cell state, 2 cells/thread

    for (int t = 0; t < NS; ++t) {
        const int* hcur = (t & 1) ? h1buf : h0buf;
        int* hnext      = (t & 1) ? h0buf : h1buf;
        const __hip_bfloat16* xt = xb + (size_t)t * NB * NF;

        // ---- x-part (independent of h_t): overlaps the barrier wait ----
        f32x4 acc0 = {0.f, 0.f, 0.f, 0.f};
        f32x4 acc1 = {0.f, 0.f, 0.f, 0.f};
        #pragma unroll
        for (int c = 0; c < 8; ++c) {
            const bf16x8 a0 = *(const bf16x8*)(xt + (size_t)row0 * NF + c * 32 + q * 8);
            const bf16x8 a1 = *(const bf16x8*)(xt + (size_t)row1 * NF + c * 32 + q * 8);
            acc0 = __builtin_amdgcn_mfma_f32_16x16x32_bf16(a0, wx[c], acc0, 0, 0, 0);
            acc1 = __builtin_amdgcn_mfma_f32_16x16x32_bf16(a1, wx[c], acc1, 0, 0, 0);
        }

        if (t > 0) wait_all(gslots, t, ENC_GROUP);

        // ---- stage this half's h_t (48 KB) into LDS, LLC-direct ----
        {
            const int4* src = (const int4*)hcur + bm * 3072;
            int4 v[12];
            #pragma unroll
            for (int i = 0; i < 12; ++i) v[i] = ld_i4_cohere(src + i * 256 + tid);
            vm_drain();
            #pragma unroll
            for (int i = 0; i < 12; ++i) {
                const int k = i * 256 + tid;          // int4 index
                const int rw = k / 96, cl = k % 96;   // row, int4-col
                *(int4*)(hst + rw * 388 + cl * 4) = v[i];
            }
        }
        __syncthreads();

        // ---- h-part MFMAs from LDS ----
        #pragma unroll
        for (int c = 0; c < 24; ++c) {
            const bf16x8 a0 = *(const bf16x8*)((const short*)hst + r * 776 + c * 32 + q * 8);
            const bf16x8 a1 = *(const bf16x8*)((const short*)hst + (r + 16) * 776 + c * 32 + q * 8);
            acc0 = __builtin_amdgcn_mfma_f32_16x16x32_bf16(a0, wh[c], acc0, 0, 0, 0);
            acc1 = __builtin_amdgcn_mfma_f32_16x16x32_bf16(a1, wh[c], acc1, 0, 0, 0);
        }

        // C/D layout: col = lane&15 (unit), row = (lane>>4)*4 + reg
        #pragma unroll
        for (int i = 0; i < 4; ++i) {
            gbuf[g][q * 4 + i][r]      = acc0[i];
            gbuf[g][16 + q * 4 + i][r] = acc1[i];
        }
        __syncthreads();

        // ---- fused cell epilogue: 2 adjacent units per thread ----
        {
            const int rowl = tid >> 3, pair = tid & 7;
            const int ua = pair * 2;
            float h2[2];
            #pragma unroll
            for (int e = 0; e < 2; ++e) {
                const int ul = ua + e;
                const float pi = gbuf[0][rowl][ul] + lbias[ul];
                const float pf = gbuf[1][rowl][ul] + lbias[16 + ul];
                const float pg = gbuf[2][rowl][ul] + lbias[32 + ul];
                const float po = gbuf[3][rowl][ul] + lbias[48 + ul];
                const float cn = sigm(pf) * cst[e] + sigm(pi) * tanhf(pg);
                h2[e] = sigm(po) * tanhf(cn);
                cst[e] = cn;
            }
            const int b = bm * 32 + rowl;
            if (t == NS - 1) {
                enc0[(size_t)b * NH + u0 + ua]     = h2[0];
                enc0[(size_t)b * NH + u0 + ua + 1] = h2[1];
                __hip_bfloat16* hf = (__hip_bfloat16*)hnext;
                hf[(size_t)b * NH + u0 + ua]     = __float2bfloat16(h2[0]);
                hf[(size_t)b * NH + u0 + ua + 1] = __float2bfloat16(h2[1]);
            } else {
                union { __hip_bfloat16 b16; unsigned short s; } c0, c1;
                c0.b16 = __float2bfloat16(h2[0]);
                c1.b16 = __float2bfloat16(h2[1]);
                const int pv = (int)c0.s | ((int)c1.s << 16);
                st_i1_cohere(hnext + (size_t)b * 384 + (u0 >> 1) + pair, pv);
            }
        }
        if (t < NS - 1) {
            vm_drain();          // h stores acked at LLC
            __syncthreads();     // all threads' stores acked
            arrive(gslots, bu, t + 1);
        }
    }
}

// One-shot LSTM step (encoder layers 1..2): gates = xin@Wx^T + b; c_prev = 0.
template<int KX, int KH>
__global__ __launch_bounds__(256) void lstm_step(
    const __hip_bfloat16* __restrict__ xin,
    const __hip_bfloat16* __restrict__ hin,
    const __hip_bfloat16* __restrict__ Wx,
    const __hip_bfloat16* __restrict__ Wh,
    const float* __restrict__ bih, const float* __restrict__ bhh,
    const float* __restrict__ c_in,
    __hip_bfloat16* __restrict__ h_bf,
    float* __restrict__ h_f32,
    float* __restrict__ c_out)
{
    constexpr int K = KX + KH;
    constexpr int NCH = K / 32;
    const int bu = blockIdx.x % (NH / 16);
    const int bm = blockIdx.x / (NH / 16);
    const int u0 = bu * 16;
    const int tid = threadIdx.x;
    const int g = tid >> 6;
    const int lane = tid & 63;
    const int r = lane & 15;
    const int q = lane >> 4;

    f32x4 acc0 = {0.f, 0.f, 0.f, 0.f};
    f32x4 acc1 = {0.f, 0.f, 0.f, 0.f};
    const int row0 = bm * 32 + r;
    const int row1 = row0 + 16;
    const long wr = (long)(g * NH + u0 + r);

    #pragma unroll
    for (int c = 0; c < NCH; ++c) {
        const int k0 = c * 32;
        bf16x8 a0, a1, bfrag;
        if (k0 < KX) {
            const int kk = k0 + q * 8;
            a0 = *(const bf16x8*)(xin + (long)row0 * KX + kk);
            a1 = *(const bf16x8*)(xin + (long)row1 * KX + kk);
            bfrag = *(const bf16x8*)(Wx + wr * KX + kk);
        } else {
            const int kk = (k0 - KX) + q * 8;
            a0 = *(const bf16x8*)(hin + (long)row0 * KH + kk);
            a1 = *(const bf16x8*)(hin + (long)row1 * KH + kk);
            bfrag = *(const bf16x8*)(Wh + wr * KH + kk);
        }
        acc0 = __builtin_amdgcn_mfma_f32_16x16x32_bf16(a0, bfrag, acc0, 0, 0, 0);
        acc1 = __builtin_amdgcn_mfma_f32_16x16x32_bf16(a1, bfrag, acc1, 0, 0, 0);
    }

    __shared__ float gbuf[4][32][17];
    #pragma unroll
    for (int i = 0; i < 4; ++i) {
        gbuf[g][q * 4 + i][r]      = acc0[i];
        gbuf[g][16 + q * 4 + i][r] = acc1[i];
    }
    __syncthreads();

    #pragma unroll
    for (int i = 0; i < 2; ++i) {
        const int idx = tid + i * 256;
        const int bl = idx >> 4;
        const int u  = idx & 15;
        const int gu = u0 + u;
        const int b  = bm * 32 + bl;
        const float pi = gbuf[0][bl][u] + bih[gu]          + bhh[gu];
        const float pf = gbuf[1][bl][u] + bih[NH + gu]     + bhh[NH + gu];
        const float pg = gbuf[2][bl][u] + bih[2 * NH + gu] + bhh[2 * NH + gu];
        const float po = gbuf[3][bl][u] + bih[3 * NH + gu] + bhh[3 * NH + gu];
        const float cp = c_in ? c_in[(long)b * NH + gu] : 0.f;
        const float cn = sigm(pf) * cp + sigm(pi) * tanhf(pg);
        const float hn = sigm(po) * tanhf(cn);
        if (c_out) c_out[(long)b * NH + gu] = cn;
        if (h_f32) h_f32[(long)b * NH + gu] = hn;
        h_bf[(long)b * NH + gu] = __float2bfloat16(hn);
    }
}

// Persistent decoder: 32 steps of a single 768-vector recurrence (layer L-1
// only; f-gate dead since c_prev==0). fp32; LLC-direct exchange; no fences.
__global__ __launch_bounds__(256) void dec_persist(
    const float* __restrict__ W,
    const float* __restrict__ bih, const float* __restrict__ bhh,
    float* __restrict__ hd0, float* __restrict__ hd1,
    float* __restrict__ hall, int* slots)
{
    __shared__ float hstD[768];
    const int tid = threadIdx.x;
    const int ul = tid >> 4;
    const int j  = tid & 15;
    const int u  = blockIdx.x * 16 + ul;
    const float* Wi = W + (size_t)u * NH;
    const float* Wg = W + (size_t)(2 * NH + u) * NH;
    const float* Wo = W + (size_t)(3 * NH + u) * NH;
    const float bi = bih[u]          + bhh[u];
    const float bg = bih[2 * NH + u] + bhh[2 * NH + u];
    const float bo = bih[3 * NH + u] + bhh[3 * NH + u];

    for (int t = 0; t < NT; ++t) {
        const float* hin = (t & 1) ? hd1 : hd0;
        float* hout      = (t & 1) ? hd0 : hd1;
        if (t > 0) wait_all(slots, t, DEC_BLOCKS);
        if (tid < 192) {
            int4 v = ld_i4_cohere((const int4*)hin + tid);
            vm_drain();
            ((int4*)hstD)[tid] = v;
        }
        __syncthreads();
        float ai = 0.f, ag = 0.f, ao = 0.f;
        for (int k = j; k < NH; k += 16) {
            const float hv = hstD[k];
            ai += hv * Wi[k];
            ag += hv * Wg[k];
            ao += hv * Wo[k];
        }
        #pragma unroll
        for (int off = 8; off > 0; off >>= 1) {
            ai += __shfl_xor(ai, off, 16);
            ag += __shfl_xor(ag, off, 16);
            ao += __shfl_xor(ao, off, 16);
        }
        if (j == 0) {
            const float cn = sigm(ai + bi) * tanhf(ag + bg);
            const float hn = sigm(ao + bo) * tanhf(cn);
            hall[(size_t)t * NH + u] = hn;             // plain (read post-dispatch)
            if (t < NT - 1)
                st_i1_cohere((int*)(hout + u), __float_as_int(hn));
        }
        if (t < NT - 1) {
            vm_drain();
            __syncthreads();
            arrive(slots, blockIdx.x, t + 1);
        }
    }
}

// Head: out[t,b,f] = hdec_all[t]@lin_W^T + lin_b, broadcast over batch.
__global__ __launch_bounds__(256) void head_kernel(
    const float* __restrict__ hall,
    const float* __restrict__ lw,
    const float* __restrict__ lb,
    float* __restrict__ out)
{
    const int t = blockIdx.x;
    const int f = threadIdx.x;
    const float* h = hall + (size_t)t * NH;
    const float4* wrow = (const float4*)(lw + (size_t)f * NH);
    float acc = 0.f;
    for (int k4 = 0; k4 < NH / 4; ++k4) {
        const float4 w = wrow[k4];
        acc += h[k4 * 4]     * w.x;
        acc += h[k4 * 4 + 1] * w.y;
        acc += h[k4 * 4 + 2] * w.z;
        acc += h[k4 * 4 + 3] * w.w;
    }
    acc += lb[f];
    float* o = out + (size_t)t * NB * NF + f;
    for (int b = 0; b < NB; ++b) o[(size_t)b * NF] = acc;
}

extern "C" void kernel_launch(void* const* d_in, const int* in_sizes, int n_in,
                              void* d_out, int out_size, void* d_ws, size_t ws_size,
                              hipStream_t stream) {
    (void)in_sizes; (void)n_in; (void)out_size; (void)ws_size;
    const float* x     = (const float*)d_in[0];
    const float* eWih0 = (const float*)d_in[1];
    const float* eWhh0 = (const float*)d_in[2];
    const float* ebih0 = (const float*)d_in[3];
    const float* ebhh0 = (const float*)d_in[4];
    const float* eWih  = (const float*)d_in[5];
    // d_in[6] = e_Whh : provably unused
    const float* ebih  = (const float*)d_in[7];
    const float* ebhh  = (const float*)d_in[8];
    const float* dWih  = (const float*)d_in[9];
    // d_in[10] = d_Whh : provably unused
    const float* dbih  = (const float*)d_in[11];
    const float* dbhh  = (const float*)d_in[12];
    const float* linW  = (const float*)d_in[13];
    const float* linb  = (const float*)d_in[14];
    float* out = (float*)d_out;

    // ---- workspace layout (bytes) ----
    char* ws = (char*)d_ws;
    __hip_bfloat16* xb   = (__hip_bfloat16*)(ws);              // 8,388,608 B
    __hip_bfloat16* W0x  = (__hip_bfloat16*)(ws +  8388608);   // 1,572,864 B
    __hip_bfloat16* W0h  = (__hip_bfloat16*)(ws +  9961472);   // 4,718,592 B
    __hip_bfloat16* eW12 = (__hip_bfloat16*)(ws + 14680064);   // 9,437,184 B
    int* hbi0 = (int*)(ws + 24117248);                         // 98,304 B (NB x 384)
    int* hbi1 = (int*)(ws + 24215552);                         // 98,304 B
    float* hd0  = (float*)(ws + 24313856);                     // 3,072 B
    float* hd1  = (float*)(ws + 24316928);                     // 3,072 B
    float* hall = (float*)(ws + 24320000);                     // 98,304 B
    int* bar    = (int*)(ws + 24418304);                       // 16,384 B
    int* enc_slots = bar;                  // 2 groups x 48 x 64 B = 6144 B
    int* dec_slots = bar + 2048;           // +8192 B: 48 x 64 B

    // zero initial states + barrier slots (ws poisoned 0xAA each call)
    (void)hipMemsetAsync(hbi0, 0, (size_t)NB * NH * 2, stream);
    (void)hipMemsetAsync(hd0, 0, (size_t)NH * 4, stream);
    (void)hipMemsetAsync(bar, 0, 16384, stream);

    // one fused fp32 -> bf16 conversion kernel (dst contiguous at ws+0)
    cvt_all<<<12058624 / 1024, 256, 0, stream>>>(x, eWih0, eWhh0, eWih,
                                                 (__hip_bfloat16*)ws);

    float* enc = out + (size_t)NT * NB * NF;                   // encoder_hidden slab

    // encoder layer 0: one persistent kernel, 256 internal steps
    enc_persist<<<ENC_BLOCKS, 256, 0, stream>>>(
        xb, W0x, W0h, ebih0, ebhh0, hbi0, hbi1, enc, enc_slots);

    // encoder layers 1..2 (final enc h lands in hbi0 viewed as bf16)
    __hip_bfloat16* hb0 = (__hip_bfloat16*)hbi0;
    __hip_bfloat16* hb1 = (__hip_bfloat16*)hbi1;
    lstm_step<NH, 0><<<96, 256, 0, stream>>>(
        hb0, nullptr, eW12, nullptr, ebih, ebhh,
        nullptr, hb1, enc + NB * NH, nullptr);
    lstm_step<NH, 0><<<96, 256, 0, stream>>>(
        hb1, nullptr, eW12 + (size_t)4 * NH * NH, nullptr,
        ebih + 4 * NH, ebhh + 4 * NH,
        nullptr, hb0, enc + 2 * (size_t)NB * NH, nullptr);

    // decoder: one persistent kernel, 32 internal steps (layer 2 only)
    const float* W2 = dWih + (size_t)2 * 4 * NH * NH;
    dec_persist<<<DEC_BLOCKS, 256, 0, stream>>>(
        W2, dbih + 2 * 4 * NH, dbhh + 2 * 4 * NH, hd0, hd1, hall, dec_slots);

    // head + batch broadcast
    head_kernel<<<NT, NF, 0, stream>>>(hall, linW, linb, out);
}